// Round 1
// baseline (355.652 us; speedup 1.0000x reference)
//
#include <hip/hip_runtime.h>
#include <hip/hip_bf16.h>

// MHA: B=2, S=2048, N_FEAT=1024, H=16, D=64
// Pipeline: f32->bf16 converts; 3 proj GEMMs (bf16 MFMA, fused layout epilogue);
// flash attention (online softmax, mask=exclude); output GEMM (f32 epilogue).

typedef float f32x4 __attribute__((ext_vector_type(4)));
typedef short bf16x8 __attribute__((ext_vector_type(8)));

typedef const __attribute__((address_space(1))) void* gas_ptr;
typedef __attribute__((address_space(3))) void* las_ptr;

static __device__ __forceinline__ short to_bf16s(float f) {
    __hip_bfloat16 h = __float2bfloat16(f);
    return __builtin_bit_cast(short, h);
}

// ---------------- f32 -> bf16 conversion (vectorized x4) ----------------
__global__ void cvt_kernel(const float* __restrict__ src, short* __restrict__ dst, int n4) {
    int i = blockIdx.x * blockDim.x + threadIdx.x;
    if (i >= n4) return;
    float4 v = reinterpret_cast<const float4*>(src)[i];
    short4 o;
    o.x = to_bf16s(v.x);
    o.y = to_bf16s(v.y);
    o.z = to_bf16s(v.z);
    o.w = to_bf16s(v.w);
    reinterpret_cast<short4*>(dst)[i] = o;
}

// ---------------- GEMM: C = A @ W^T + bias ----------------
// A: M x K bf16 row-major.  W: N x K bf16 row-major (so both stage identically).
// 128x128 tile, BK=32, 4 waves (2x2), each wave 64x64 via 4x4 16x16x32 MFMA frags.
// EPI: 0 = bf16 out in (B,H,S,64) head-major; 1 = bf16 out in (B,H,64,S) (V^T);
//      2 = f32 out row-major (final output).
template <int EPI>
__global__ __launch_bounds__(256, 2) void gemm_nt(
    const short* __restrict__ A, const short* __restrict__ W,
    const float* __restrict__ bias, void* __restrict__ outp,
    int M, int N, int K)
{
    __shared__ __align__(16) short lds_a[128 * 32];
    __shared__ __align__(16) short lds_b[128 * 32];
    const int tid = threadIdx.x;
    const int w = tid >> 6, l = tid & 63;
    const int lr = l & 15, lh = l >> 4;
    const int m0 = blockIdx.x * 128, n0 = blockIdx.y * 128;
    const int wr = (w >> 1) * 64, wc = (w & 1) * 64;

    f32x4 acc[4][4] = {};

    // staging: 8KB per tile = 2 rounds of 256 threads x 16B
    const int idx0 = tid, idx1 = 256 + tid;
    const int r0 = idx0 >> 2, c0 = (idx0 & 3) * 8;
    const int r1 = idx1 >> 2, c1 = (idx1 & 3) * 8;
    const short* ga0 = A + (long)(m0 + r0) * K + c0;
    const short* ga1 = A + (long)(m0 + r1) * K + c1;
    const short* gb0 = W + (long)(n0 + r0) * K + c0;
    const short* gb1 = W + (long)(n0 + r1) * K + c1;

    for (int k0 = 0; k0 < K; k0 += 32) {
        // async global -> LDS, 16B/lane, wave-uniform LDS base (linear layout)
        __builtin_amdgcn_global_load_lds((gas_ptr)(ga0 + k0), (las_ptr)(lds_a + w * 512), 16, 0, 0);
        __builtin_amdgcn_global_load_lds((gas_ptr)(ga1 + k0), (las_ptr)(lds_a + 2048 + w * 512), 16, 0, 0);
        __builtin_amdgcn_global_load_lds((gas_ptr)(gb0 + k0), (las_ptr)(lds_b + w * 512), 16, 0, 0);
        __builtin_amdgcn_global_load_lds((gas_ptr)(gb1 + k0), (las_ptr)(lds_b + 2048 + w * 512), 16, 0, 0);
        __syncthreads();  // drains vmcnt before barrier -> LDS ready

        bf16x8 af[4], bfr[4];
#pragma unroll
        for (int i = 0; i < 4; ++i)
            af[i] = *reinterpret_cast<const bf16x8*>(lds_a + (wr + i * 16 + lr) * 32 + lh * 8);
#pragma unroll
        for (int i = 0; i < 4; ++i)
            bfr[i] = *reinterpret_cast<const bf16x8*>(lds_b + (wc + i * 16 + lr) * 32 + lh * 8);
#pragma unroll
        for (int i = 0; i < 4; ++i)
#pragma unroll
            for (int j = 0; j < 4; ++j)
                acc[i][j] = __builtin_amdgcn_mfma_f32_16x16x32_bf16(af[i], bfr[j], acc[i][j], 0, 0, 0);
        __syncthreads();  // all waves done reading before next stage overwrites
    }

    // epilogue: C/D layout col = lane&15, row = (lane>>4)*4 + reg  [m89-verified]
#pragma unroll
    for (int i = 0; i < 4; ++i) {
#pragma unroll
        for (int j = 0; j < 4; ++j) {
#pragma unroll
            for (int r = 0; r < 4; ++r) {
                const int row = m0 + wr + i * 16 + lh * 4 + r;  // M index (b*2048+s)
                const int col = n0 + wc + j * 16 + lr;          // N index (h*64+d)
                float v = acc[i][j][r] + bias[col];
                if constexpr (EPI == 0) {
                    const int b = row >> 11, s = row & 2047;
                    const int h = col >> 6, d = col & 63;
                    ((short*)outp)[(((long)(b * 16 + h)) * 2048 + s) * 64 + d] = to_bf16s(v);
                } else if constexpr (EPI == 1) {
                    const int b = row >> 11, s = row & 2047;
                    const int h = col >> 6, d = col & 63;
                    ((short*)outp)[(((long)(b * 16 + h)) * 64 + d) * 2048 + s] = to_bf16s(v);
                } else {
                    ((float*)outp)[(long)row * N + col] = v;
                }
            }
        }
    }
}

// ---------------- flash attention ----------------
// grid (S/64, B*H), 256 threads (4 waves). Wave w owns 16 q-rows.
// Q,K in (B*H, S, 64) bf16; V^T in (B*H, 64, S) bf16; mask int32 (B,S), nonzero = masked.
// X out: (B, S, 1024) bf16 row-major.
__global__ __launch_bounds__(256, 2) void attn_kernel(
    const short* __restrict__ Q, const short* __restrict__ Kmat,
    const short* __restrict__ Vt, const int* __restrict__ mask,
    short* __restrict__ X)
{
    __shared__ __align__(16) short lds_p[4][16 * 40];  // per-wave P tile, stride 40 (bank-friendly)
    const int bh = blockIdx.y;
    const int b = bh >> 4, h = bh & 15;
    const int q0 = blockIdx.x * 64;
    const int w = threadIdx.x >> 6, l = threadIdx.x & 63;
    const int lr = l & 15, lh = l >> 4;

    // Q fragments (A-layout: row = lane&15, k = (lane>>4)*8 + i)
    const short* Qp = Q + ((long)bh * 2048 + q0 + w * 16 + lr) * 64 + lh * 8;
    const bf16x8 qf0 = *reinterpret_cast<const bf16x8*>(Qp);
    const bf16x8 qf1 = *reinterpret_cast<const bf16x8*>(Qp + 32);

    f32x4 ao[4] = {};
    float m[4], ls[4];
#pragma unroll
    for (int j = 0; j < 4; ++j) { m[j] = -1e30f; ls[j] = 0.f; }

    const int* mp = mask + (long)b * 2048;
    const short* Kbase = Kmat + (long)bh * 2048 * 64 + (long)lr * 64 + lh * 8;
    const short* Vbase = Vt + ((long)bh * 64 + lr) * 2048 + lh * 8;

    for (int kb = 0; kb < 64; ++kb) {
        const int key0 = kb * 32;
        // S = Q K^T for 16q x 32k (two 16-key tiles), K-dim = D = 64 (2 steps)
        f32x4 sc0 = {}, sc1 = {};
        {
            const short* Kp0 = Kbase + (long)key0 * 64;
            bf16x8 ka = *reinterpret_cast<const bf16x8*>(Kp0);
            bf16x8 kc = *reinterpret_cast<const bf16x8*>(Kp0 + 32);
            sc0 = __builtin_amdgcn_mfma_f32_16x16x32_bf16(qf0, ka, sc0, 0, 0, 0);
            sc0 = __builtin_amdgcn_mfma_f32_16x16x32_bf16(qf1, kc, sc0, 0, 0, 0);
            const short* Kp1 = Kp0 + 16 * 64;
            ka = *reinterpret_cast<const bf16x8*>(Kp1);
            kc = *reinterpret_cast<const bf16x8*>(Kp1 + 32);
            sc1 = __builtin_amdgcn_mfma_f32_16x16x32_bf16(qf0, ka, sc1, 0, 0, 0);
            sc1 = __builtin_amdgcn_mfma_f32_16x16x32_bf16(qf1, kc, sc1, 0, 0, 0);
        }
        const bool mk0 = mp[key0 + lr] != 0;
        const bool mk1 = mp[key0 + 16 + lr] != 0;

        float scl[4];
#pragma unroll
        for (int j = 0; j < 4; ++j) {
            float s0 = mk0 ? -1e30f : sc0[j] * 0.125f;
            float s1 = mk1 ? -1e30f : sc1[j] * 0.125f;
            float t = fmaxf(s0, s1);
            t = fmaxf(t, __shfl_xor(t, 1));
            t = fmaxf(t, __shfl_xor(t, 2));
            t = fmaxf(t, __shfl_xor(t, 4));
            t = fmaxf(t, __shfl_xor(t, 8));
            const float mn = fmaxf(m[j], t);
            const float sf = __expf(m[j] - mn);       // -1e30 - (-1e30) = 0 -> 1 (acc is 0), ok
            const float p0 = mk0 ? 0.f : __expf(s0 - mn);
            const float p1 = mk1 ? 0.f : __expf(s1 - mn);
            float ps = p0 + p1;
            ps += __shfl_xor(ps, 1);
            ps += __shfl_xor(ps, 2);
            ps += __shfl_xor(ps, 4);
            ps += __shfl_xor(ps, 8);
            ls[j] = ls[j] * sf + ps;
            m[j] = mn;
            scl[j] = sf;
            const int prow = lh * 4 + j;  // C-layout row
            lds_p[w][prow * 40 + lr] = to_bf16s(p0);
            lds_p[w][prow * 40 + 16 + lr] = to_bf16s(p1);
        }
#pragma unroll
        for (int dt = 0; dt < 4; ++dt)
#pragma unroll
            for (int j = 0; j < 4; ++j) ao[dt][j] *= scl[j];

        __syncthreads();  // make this wave's ds_writes visible cross-lane before A-layout read

        const bf16x8 pa = *reinterpret_cast<const bf16x8*>(&lds_p[w][lr * 40 + lh * 8]);
        const short* Vp = Vbase + key0;
#pragma unroll
        for (int dt = 0; dt < 4; ++dt) {
            bf16x8 vf = *reinterpret_cast<const bf16x8*>(Vp + (long)dt * 16 * 2048);
            ao[dt] = __builtin_amdgcn_mfma_f32_16x16x32_bf16(pa, vf, ao[dt], 0, 0, 0);
        }
    }

    // epilogue: X[b, s, h*64 + d] = ao / l  (0 if row fully masked)
#pragma unroll
    for (int j = 0; j < 4; ++j) {
        const float inv = 1.0f / fmaxf(ls[j], 1e-30f);
        const int s = q0 + w * 16 + lh * 4 + j;
        short* Xp = X + ((long)b * 2048 + s) * 1024 + h * 64;
#pragma unroll
        for (int dt = 0; dt < 4; ++dt)
            Xp[dt * 16 + lr] = to_bf16s(ao[dt][j] * inv);
    }
}

// ---------------- launch ----------------
extern "C" void kernel_launch(void* const* d_in, const int* in_sizes, int n_in,
                              void* d_out, int out_size, void* d_ws, size_t ws_size,
                              hipStream_t stream) {
    const float* query = (const float*)d_in[0];
    const float* key_  = (const float*)d_in[1];
    const float* value = (const float*)d_in[2];
    const int*   mask  = (const int*)d_in[3];
    const float* w_q = (const float*)d_in[4];
    const float* b_q = (const float*)d_in[5];
    const float* w_k = (const float*)d_in[6];
    const float* b_k = (const float*)d_in[7];
    const float* w_v = (const float*)d_in[8];
    const float* b_v = (const float*)d_in[9];
    const float* w_o = (const float*)d_in[10];
    const float* b_o = (const float*)d_in[11];

    const long SEQ = 4194304;  // 4096*1024 elements
    const long WSZ = 1048576;  // 1024*1024
    short* ws = (short*)d_ws;
    short* cq = ws;            // converted query
    short* ck = cq + SEQ;
    short* cv = ck + SEQ;
    short* wq = cv + SEQ;
    short* wk = wq + WSZ;
    short* wv = wk + WSZ;
    short* wo = wv + WSZ;
    short* Qb = wo + WSZ;      // (B,H,S,64)
    short* Kb = Qb + SEQ;
    short* Vt = Kb + SEQ;      // (B,H,64,S)
    short* Xb = cq;            // reuse: cq dead after Q-projection

    cvt_kernel<<<4096, 256, 0, stream>>>(query, cq, 1048576);
    cvt_kernel<<<4096, 256, 0, stream>>>(key_, ck, 1048576);
    cvt_kernel<<<4096, 256, 0, stream>>>(value, cv, 1048576);
    cvt_kernel<<<1024, 256, 0, stream>>>(w_q, wq, 262144);
    cvt_kernel<<<1024, 256, 0, stream>>>(w_k, wk, 262144);
    cvt_kernel<<<1024, 256, 0, stream>>>(w_v, wv, 262144);
    cvt_kernel<<<1024, 256, 0, stream>>>(w_o, wo, 262144);

    dim3 blk(256);
    dim3 gP(32, 8);  // M=4096 / 128, N=1024 / 128
    gemm_nt<0><<<gP, blk, 0, stream>>>(cq, wq, b_q, Qb, 4096, 1024, 1024);
    gemm_nt<0><<<gP, blk, 0, stream>>>(ck, wk, b_k, Kb, 4096, 1024, 1024);
    gemm_nt<1><<<gP, blk, 0, stream>>>(cv, wv, b_v, Vt, 4096, 1024, 1024);

    attn_kernel<<<dim3(32, 32), blk, 0, stream>>>(Qb, Kb, Vt, mask, Xb);

    gemm_nt<2><<<gP, blk, 0, stream>>>(Xb, wo, b_o, d_out, 4096, 1024, 1024);
}